// Round 1
// baseline (835.471 us; speedup 1.0000x reference)
//
#include <hip/hip_runtime.h>
#include <cstdint>
#include <cmath>

// ---------------------------------------------------------------------------
// Fused attention block for MI355X (gfx950).
// B=2, N=2048, D=2048, H=16, DH=128.  All inputs fp32; compute in fp16 MFMA
// (fp32 accum) — threshold is 2% of max|ref| which fp16 clears with ~2x margin.
// Pipeline:
//   1. cvt_x:      x fp32 -> xh fp16 (4096 x 2048 row-major)
//   2. transpose4: Wq,Wk,Wv,Wo fp32 (K x N) -> fp16 (N x K)   ("Bt" layout)
//   3. gemm_bt x3: qh,kh (B,H,N,DH) fp16;  vt (B,H,DH,N) fp16
//   4. rope:       in-place RoPE on qh, kh
//   5. gate:       sigmoid(x @ Wg + bg) -> (B,H,N) fp32
//   6. attn:       flash attention + gating -> attn (4096 x 2048) fp16
//   7. gemm_bt:    attn @ Wo -> d_out fp32
// MFMA fragment layouts (HW-verified, learn_hip m89/m91/m120):
//   C/D: col = lane&15, row = (lane>>4)*4 + reg
//   A:   m  = lane&15, k = (lane>>4)*8 + j
//   B:   n  = lane&15, k = (lane>>4)*8 + j   (i.e. B^T rows, contiguous k)
// ---------------------------------------------------------------------------

typedef _Float16 h8   __attribute__((ext_vector_type(8)));
typedef _Float16 h4   __attribute__((ext_vector_type(4)));
typedef float    f32x4 __attribute__((ext_vector_type(4)));

#define NB   2
#define NN   2048
#define ND   2048
#define NH   16
#define NDH  128
#define BNR  4096            // B*N rows
#define KDIM 2048
#define ATT_SCALE 0.08838834764831845f   // 128^-0.5

// ---------------- 1. convert x to fp16 ----------------
__global__ __launch_bounds__(256) void cvt_x(const float* __restrict__ x,
                                             _Float16* __restrict__ xh) {
  int i = blockIdx.x * 256 + threadIdx.x;          // i < BNR*ND/4
  float4 v = ((const float4*)x)[i];
  h4 o;
  o[0] = (_Float16)v.x; o[1] = (_Float16)v.y;
  o[2] = (_Float16)v.z; o[3] = (_Float16)v.w;
  ((h4*)xh)[i] = o;
}

// ---------------- 2. transpose weights (K x N fp32) -> (N x K fp16) --------
__global__ __launch_bounds__(256) void transpose4(
    const float* __restrict__ W0, const float* __restrict__ W1,
    const float* __restrict__ W2, const float* __restrict__ W3,
    _Float16* __restrict__ T0, _Float16* __restrict__ T1,
    _Float16* __restrict__ T2, _Float16* __restrict__ T3) {
  const float* W; _Float16* T;
  switch (blockIdx.z) {
    case 0: W = W0; T = T0; break;
    case 1: W = W1; T = T1; break;
    case 2: W = W2; T = T2; break;
    default: W = W3; T = T3; break;
  }
  __shared__ float tile[32][33];
  int tx = threadIdx.x, ty = threadIdx.y;          // block (32,8)
  int n0 = blockIdx.x * 32, k0 = blockIdx.y * 32;
#pragma unroll
  for (int j = 0; j < 4; ++j)
    tile[ty + j * 8][tx] = W[(size_t)(k0 + ty + j * 8) * ND + n0 + tx];
  __syncthreads();
#pragma unroll
  for (int j = 0; j < 4; ++j)
    T[(size_t)(n0 + ty + j * 8) * KDIM + k0 + tx] =
        (_Float16)tile[tx][ty + j * 8];
}

// ---------------- 3/7. GEMM: C(4096x2048) = A(4096x2048) * Bt(2048x2048)^T -
// mode 0: dst fp16 laid out (B,H,N,DH)      (Q/K projection)
// mode 1: dst fp16 laid out (B,H,DH,N)      (V projection, pre-transposed)
// mode 2: dst fp32 row-major (4096x2048)    (output projection)
__global__ __launch_bounds__(256) void gemm_bt(
    const _Float16* __restrict__ A, const _Float16* __restrict__ Bt,
    void* __restrict__ dst, int mode) {
  __shared__ __align__(16) _Float16 As[128][40];   // +8 pad: 80B row stride
  __shared__ __align__(16) _Float16 Bs[128][40];
  int bx = blockIdx.x, by = blockIdx.y;
  int tid = threadIdx.x;
  int wave = tid >> 6, lane = tid & 63, li = lane & 15, quad = lane >> 4;
  int wm = (wave >> 1) * 64, wn = (wave & 1) * 64;
  int row0 = by * 128, col0 = bx * 128;
  f32x4 acc[4][4] = {};

  for (int k0 = 0; k0 < KDIM; k0 += 32) {
    __syncthreads();
#pragma unroll
    for (int s = 0; s < 2; ++s) {
      int c = tid + s * 256;                 // 512 chunks of 16B per tile
      int row = c >> 2, col8 = (c & 3) * 8;
      *(h8*)&As[row][col8] =
          *(const h8*)&A[(size_t)(row0 + row) * KDIM + k0 + col8];
      *(h8*)&Bs[row][col8] =
          *(const h8*)&Bt[(size_t)(col0 + row) * KDIM + k0 + col8];
    }
    __syncthreads();
    h8 af[4], bf[4];
#pragma unroll
    for (int mi = 0; mi < 4; ++mi)
      af[mi] = *(const h8*)&As[wm + mi * 16 + li][quad * 8];
#pragma unroll
    for (int ni = 0; ni < 4; ++ni)
      bf[ni] = *(const h8*)&Bs[wn + ni * 16 + li][quad * 8];
#pragma unroll
    for (int mi = 0; mi < 4; ++mi)
#pragma unroll
      for (int ni = 0; ni < 4; ++ni)
        acc[mi][ni] = __builtin_amdgcn_mfma_f32_16x16x32_f16(
            af[mi], bf[ni], acc[mi][ni], 0, 0, 0);
  }

  // epilogue
#pragma unroll
  for (int mi = 0; mi < 4; ++mi) {
    int gmb = row0 + wm + mi * 16 + quad * 4;   // 4 consecutive output rows
#pragma unroll
    for (int ni = 0; ni < 4; ++ni) {
      int gn = col0 + wn + ni * 16 + li;
      if (mode == 2) {
        float* o = (float*)dst;
#pragma unroll
        for (int r = 0; r < 4; ++r)
          o[(size_t)(gmb + r) * ND + gn] = acc[mi][ni][r];
      } else if (mode == 0) {
        _Float16* o = (_Float16*)dst;
        int h = gn >> 7, d = gn & 127;
#pragma unroll
        for (int r = 0; r < 4; ++r) {
          int gm = gmb + r, b = gm >> 11, n = gm & 2047;
          o[((size_t)(b * NH + h) * NN + n) * NDH + d] =
              (_Float16)acc[mi][ni][r];
        }
      } else {  // mode 1: V transposed (B,H,DH,N); 4 consecutive n -> 8B store
        _Float16* o = (_Float16*)dst;
        int h = gn >> 7, d = gn & 127;
        int b = gmb >> 11, n0 = gmb & 2047;
        h4 tmp;
#pragma unroll
        for (int r = 0; r < 4; ++r) tmp[r] = (_Float16)acc[mi][ni][r];
        *(h4*)&o[((size_t)(b * NH + h) * NDH + d) * NN + n0] = tmp;
      }
    }
  }
}

// ---------------- 4. RoPE on qh, kh (in place, (B,H,N,DH) fp16) ------------
__global__ __launch_bounds__(256) void rope_kernel(
    _Float16* __restrict__ qh, _Float16* __restrict__ kh,
    const float* __restrict__ freqs) {
  int i = blockIdx.x * 256 + threadIdx.x;   // B*H*N*64 threads, one (d,d+64) pair
  int d = i & 63;
  int rest = i >> 6;
  int n = rest & 2047;
  int bh = rest >> 11;
  size_t base = (size_t)bh * NN * NDH + (size_t)n * NDH;
  float f1 = freqs[n * NDH + d], f2 = freqs[n * NDH + d + 64];
  float c1 = cosf(f1), s1 = sinf(f1);
  float c2 = cosf(f2), s2 = sinf(f2);
  float q1 = (float)qh[base + d], q2 = (float)qh[base + d + 64];
  qh[base + d]      = (_Float16)(q1 * c1 - q2 * s1);
  qh[base + d + 64] = (_Float16)(q2 * c2 + q1 * s2);
  float k1 = (float)kh[base + d], k2 = (float)kh[base + d + 64];
  kh[base + d]      = (_Float16)(k1 * c1 - k2 * s1);
  kh[base + d + 64] = (_Float16)(k2 * c2 + k1 * s2);
}

// ---------------- 5. gate = sigmoid(x @ Wg + bg), stored (B,H,N) fp32 ------
__global__ __launch_bounds__(256) void gate_kernel(
    const float* __restrict__ x, const float* __restrict__ Wg,
    const float* __restrict__ bg, float* __restrict__ gate) {
  int m = blockIdx.x;                       // token row 0..4095
  __shared__ float xr[2048];
  for (int i = threadIdx.x; i < 2048; i += 256)
    xr[i] = x[(size_t)m * KDIM + i];
  __syncthreads();
  int wave = threadIdx.x >> 6, lane = threadIdx.x & 63;
#pragma unroll
  for (int hh = 0; hh < 4; ++hh) {
    int h = wave * 4 + hh;
    float s = 0.f;
    for (int k = lane; k < 2048; k += 64) s += xr[k] * Wg[k * NH + h];
#pragma unroll
    for (int off = 32; off; off >>= 1) s += __shfl_xor(s, off, 64);
    if (lane == 0) {
      float g = s + bg[h];
      int b = m >> 11, n = m & 2047;
      gate[(size_t)(b * NH + h) * NN + n] = 1.f / (1.f + expf(-g));
    }
  }
}

// ---------------- 6. flash attention + gating ------------------------------
// grid: B*H*(N/64) blocks; 4 waves/block; wave owns 16 q-rows.
__global__ __launch_bounds__(256) void attn_kernel(
    const _Float16* __restrict__ qh, const _Float16* __restrict__ kh,
    const _Float16* __restrict__ vt, const float* __restrict__ gate,
    _Float16* __restrict__ attn) {
  __shared__ __align__(16) _Float16 Ks[32][136];   // kv x dh (+8 pad)
  __shared__ __align__(16) _Float16 Vs[128][40];   // dh x kv (+8 pad)
  __shared__ __align__(16) _Float16 Ps[4][16][40]; // per-wave P relayout
  int bh = blockIdx.x >> 5, qblk = blockIdx.x & 31;
  int tid = threadIdx.x, wave = tid >> 6, lane = tid & 63;
  int li = lane & 15, quad = lane >> 4;
  int q0 = qblk * 64 + wave * 16;
  const _Float16* qb = qh + (size_t)bh * NN * NDH;
  const _Float16* kb = kh + (size_t)bh * NN * NDH;
  const _Float16* vb = vt + (size_t)bh * NDH * NN;

  h8 aq[4];
#pragma unroll
  for (int kk = 0; kk < 4; ++kk)
    aq[kk] = *(const h8*)&qb[(size_t)(q0 + li) * NDH + kk * 32 + quad * 8];

  float m_r[4] = {-INFINITY, -INFINITY, -INFINITY, -INFINITY};
  float l_r[4] = {0.f, 0.f, 0.f, 0.f};
  f32x4 o[8] = {};

  for (int kv0 = 0; kv0 < NN; kv0 += 32) {
    __syncthreads();
#pragma unroll
    for (int s = 0; s < 2; ++s) {
      int c = tid + s * 256;
      {  // K tile: 32 rows x 128 dh = 512 x 16B chunks
        int row = c >> 4, col8 = (c & 15) * 8;
        *(h8*)&Ks[row][col8] =
            *(const h8*)&kb[(size_t)(kv0 + row) * NDH + col8];
      }
      {  // V^T tile: 128 rows(dh) x 32 kv = 512 x 16B chunks
        int row = c >> 2, col8 = (c & 3) * 8;
        *(h8*)&Vs[row][col8] =
            *(const h8*)&vb[(size_t)row * NN + kv0 + col8];
      }
    }
    __syncthreads();

    // S = Q K^T for this wave's 16 rows x 32 kv
    f32x4 s0 = {}, s1 = {};
#pragma unroll
    for (int kk = 0; kk < 4; ++kk) {
      h8 b0 = *(const h8*)&Ks[li][kk * 32 + quad * 8];
      h8 b1 = *(const h8*)&Ks[16 + li][kk * 32 + quad * 8];
      s0 = __builtin_amdgcn_mfma_f32_16x16x32_f16(aq[kk], b0, s0, 0, 0, 0);
      s1 = __builtin_amdgcn_mfma_f32_16x16x32_f16(aq[kk], b1, s1, 0, 0, 0);
    }

    // online softmax (rows = quad*4 + r; cols = {0,1}*16 + li)
    float p0[4], p1[4], alpha[4];
#pragma unroll
    for (int r = 0; r < 4; ++r) {
      float sv0 = s0[r] * ATT_SCALE, sv1 = s1[r] * ATT_SCALE;
      float t = fmaxf(sv0, sv1);
      t = fmaxf(t, __shfl_xor(t, 1, 64));
      t = fmaxf(t, __shfl_xor(t, 2, 64));
      t = fmaxf(t, __shfl_xor(t, 4, 64));
      t = fmaxf(t, __shfl_xor(t, 8, 64));
      float mn = fmaxf(m_r[r], t);
      alpha[r] = __expf(m_r[r] - mn);
      m_r[r] = mn;
      p0[r] = __expf(sv0 - mn);
      p1[r] = __expf(sv1 - mn);
      float rs = p0[r] + p1[r];
      rs += __shfl_xor(rs, 1, 64);
      rs += __shfl_xor(rs, 2, 64);
      rs += __shfl_xor(rs, 4, 64);
      rs += __shfl_xor(rs, 8, 64);
      l_r[r] = l_r[r] * alpha[r] + rs;
    }
#pragma unroll
    for (int ni = 0; ni < 8; ++ni)
#pragma unroll
      for (int r = 0; r < 4; ++r) o[ni][r] *= alpha[r];

    // P -> A-fragment layout via per-wave LDS (wave-synchronous, no barrier)
#pragma unroll
    for (int r = 0; r < 4; ++r) {
      Ps[wave][quad * 4 + r][li] = (_Float16)p0[r];
      Ps[wave][quad * 4 + r][16 + li] = (_Float16)p1[r];
    }
    h8 pa = *(const h8*)&Ps[wave][li][quad * 8];
#pragma unroll
    for (int ni = 0; ni < 8; ++ni) {
      h8 vbv = *(const h8*)&Vs[ni * 16 + li][quad * 8];
      o[ni] = __builtin_amdgcn_mfma_f32_16x16x32_f16(pa, vbv, o[ni], 0, 0, 0);
    }
  }

  // epilogue: normalize, gate, store to (B, N, H*DH) fp16
  int b = bh >> 4, h = bh & 15;
#pragma unroll
  for (int r = 0; r < 4; ++r) {
    int qrow = q0 + quad * 4 + r;
    float g = gate[(size_t)bh * NN + qrow] / l_r[r];
#pragma unroll
    for (int ni = 0; ni < 8; ++ni)
      attn[((size_t)(b * NN + qrow)) * ND + h * NDH + ni * 16 + li] =
          (_Float16)(o[ni][r] * g);
  }
}

// ---------------------------------------------------------------------------
extern "C" void kernel_launch(void* const* d_in, const int* in_sizes, int n_in,
                              void* d_out, int out_size, void* d_ws,
                              size_t ws_size, hipStream_t stream) {
  const float* x    = (const float*)d_in[0];
  const float* rpe  = (const float*)d_in[1];
  const float* Wq   = (const float*)d_in[2];
  const float* Wk   = (const float*)d_in[3];
  const float* Wv   = (const float*)d_in[4];
  const float* Wg   = (const float*)d_in[5];
  const float* bg   = (const float*)d_in[6];
  const float* Wo   = (const float*)d_in[7];
  float* out = (float*)d_out;

  char* ws = (char*)d_ws;
  size_t off = 0;
  auto alloc = [&](size_t bytes) {
    void* p = ws + off;
    off += (bytes + 255) & ~(size_t)255;
    return p;
  };
  _Float16* xh   = (_Float16*)alloc((size_t)BNR * KDIM * 2);   // 16 MB
  _Float16* Wqt  = (_Float16*)alloc((size_t)ND * KDIM * 2);    // 8 MB
  _Float16* Wkt  = (_Float16*)alloc((size_t)ND * KDIM * 2);
  _Float16* Wvt  = (_Float16*)alloc((size_t)ND * KDIM * 2);
  _Float16* Wot  = (_Float16*)alloc((size_t)ND * KDIM * 2);
  _Float16* qh   = (_Float16*)alloc((size_t)NB * NH * NN * NDH * 2); // 16 MB
  _Float16* kh   = (_Float16*)alloc((size_t)NB * NH * NN * NDH * 2);
  _Float16* vt   = (_Float16*)alloc((size_t)NB * NH * NDH * NN * 2);
  _Float16* attn = (_Float16*)alloc((size_t)BNR * ND * 2);     // 16 MB
  float*    gate = (float*)alloc((size_t)NB * NH * NN * 4);    // 256 KB

  cvt_x<<<BNR * KDIM / 1024, 256, 0, stream>>>(x, xh);
  transpose4<<<dim3(64, 64, 4), dim3(32, 8), 0, stream>>>(
      Wq, Wk, Wv, Wo, Wqt, Wkt, Wvt, Wot);
  gemm_bt<<<dim3(16, 32), 256, 0, stream>>>(xh, Wqt, qh, 0);
  gemm_bt<<<dim3(16, 32), 256, 0, stream>>>(xh, Wkt, kh, 0);
  gemm_bt<<<dim3(16, 32), 256, 0, stream>>>(xh, Wvt, vt, 1);
  rope_kernel<<<NB * NH * NN * 64 / 256, 256, 0, stream>>>(qh, kh, rpe);
  gate_kernel<<<BNR, 256, 0, stream>>>(x, Wg, bg, gate);
  attn_kernel<<<NB * NH * (NN / 64), 256, 0, stream>>>(qh, kh, vt, gate, attn);
  gemm_bt<<<dim3(16, 32), 256, 0, stream>>>(attn, Wot, out, 2);
}